// Round 4
// baseline (412.210 us; speedup 1.0000x reference)
//
#include <hip/hip_runtime.h>

// Problem: points [B=32, N=8192, 3] f32.
//   FPS -> K=128 centers/batch (start idx 0); KNN -> P=32 nearest points per
//   center, ascending d2, ties by lower index.
//
// Output d_out is FLOAT32 (mixed int32/float32 tuple promotes to f32; the
// "bf16" in the harness error label is hard-coded text). Flat concat in
// return order:
//   out[0 .. 131072)        = idx   [B,K,P] as float
//   out[131072 .. 143360)   = centers [B,K,3] as float
// (All four failing rounds' absmax values reproduce bit-exactly under this
//  model — see journal.)
#define BB 32
#define NN 8192
#define KK 128
#define PP 32
#define IDX_COUNT (BB * KK * PP)   // 131072

// ---------------------------------------------------------------------------
// Kernel 1: farthest point sampling. One block per batch, 1024 threads,
// 8 points per thread in registers. Bit-parity with the numpy scan:
//   emit last; d = (dx*dx+dy*dy)+dz*dz (no FMA); mind = min(mind,d);
//   next = argmax(mind), first-index tie-break.
// Writes f32 centers straight into d_out's center region.
// ---------------------------------------------------------------------------
__global__ __launch_bounds__(1024) void fps_kernel(
    const float* __restrict__ pts,
    float* __restrict__ out)
{
#pragma clang fp contract(off)
    const int b = blockIdx.x;
    const int t = threadIdx.x;
    const float* p = pts + (size_t)b * NN * 3;

    float px[8], py[8], pz[8], mind[8];
#pragma unroll
    for (int i = 0; i < 8; ++i) {
        int idx = t + i * 1024;
        px[i] = p[idx * 3 + 0];
        py[i] = p[idx * 3 + 1];
        pz[i] = p[idx * 3 + 2];
        mind[i] = __builtin_inff();
    }

    __shared__ float bc[3];
    __shared__ unsigned long long wk[16];
    __shared__ unsigned long long fin;
    const int lane = t & 63;
    const int wid  = t >> 6;

    unsigned last = 0;  // deterministic start at index 0
    for (int k = 0; k < KK; ++k) {
        if ((last & 1023u) == (unsigned)t) {   // unique owner publishes center
            int i = (int)(last >> 10);
            bc[0] = px[i]; bc[1] = py[i]; bc[2] = pz[i];
            int c = b * KK + k;
            out[IDX_COUNT + c * 3 + 0] = px[i];
            out[IDX_COUNT + c * 3 + 1] = py[i];
            out[IDX_COUNT + c * 3 + 2] = pz[i];
        }
        __syncthreads();
        const float lx = bc[0], ly = bc[1], lz = bc[2];

        // mind update + packed (val, ~idx) max key (vals >= 0: bit order ok).
        unsigned long long key = 0;
#pragma unroll
        for (int i = 0; i < 8; ++i) {
            float dx = px[i] - lx, dy = py[i] - ly, dz = pz[i] - lz;
            float d = (dx * dx + dy * dy) + dz * dz;
            float m = mind[i] < d ? mind[i] : d;
            mind[i] = m;
            union { float f; unsigned u; } cv; cv.f = m;
            unsigned long long kk = ((unsigned long long)cv.u << 32)
                                  | (0xFFFFFFFFu - (unsigned)(t + i * 1024));
            if (kk > key) key = kk;   // ties: larger complement = smaller idx
        }
#pragma unroll
        for (int off = 32; off; off >>= 1) {
            unsigned long long o = __shfl_down(key, off, 64);
            if (o > key) key = o;
        }
        if (lane == 0) wk[wid] = key;
        __syncthreads();
        if (wid == 0) {
            unsigned long long v = (lane < 16) ? wk[lane] : 0ull;
#pragma unroll
            for (int off = 8; off; off >>= 1) {
                unsigned long long o = __shfl_down(v, off, 64);
                if (o > v) v = o;
            }
            if (lane == 0) fin = v;
        }
        __syncthreads();
        last = 0xFFFFFFFFu - (unsigned)(fin & 0xFFFFFFFFu);
    }
}

// ---------------------------------------------------------------------------
// Kernel 2: brute-force KNN. One block per (b,k), 256 threads, 32
// points/thread. d2 mirrors numpy: (cc+pp) - 2*dot, no FMA, -0.0
// canonicalized. Top-32 ascending via 32 rounds of block-wide u64 min-reduce
// with "key > prev" exclusion (keys unique via idx low bits).
// Reads centers from d_out (written by fps_kernel on the same stream).
// ---------------------------------------------------------------------------
__global__ __launch_bounds__(256) void knn_kernel(
    const float* __restrict__ pts,
    float* __restrict__ out)
{
#pragma clang fp contract(off)
    const int bk = blockIdx.x;         // b*K + k
    const int b  = bk >> 7;
    const int t  = threadIdx.x;
    const float* p = pts + (size_t)b * NN * 3;

    const float cx = out[IDX_COUNT + bk * 3 + 0];
    const float cy = out[IDX_COUNT + bk * 3 + 1];
    const float cz = out[IDX_COUNT + bk * 3 + 2];
    const float cc = (cx * cx + cy * cy) + cz * cz;

    unsigned o[32];  // ordered-uint keys for d2 (monotone incl. negatives)
#pragma unroll
    for (int i = 0; i < 32; ++i) {
        int idx = t + i * 256;
        float x = p[idx * 3 + 0], y = p[idx * 3 + 1], z = p[idx * 3 + 2];
        float pp = (x * x + y * y) + z * z;
        float dot = (cx * x + cy * y) + cz * z;
        float d2 = (cc + pp) - (2.0f * dot);
        d2 = d2 + 0.0f;                 // -0.0 -> +0.0 (tie order parity)
        union { float f; unsigned u; } cv; cv.f = d2;
        unsigned u = cv.u;
        o[i] = (u & 0x80000000u) ? ~u : (u | 0x80000000u);
    }

    __shared__ unsigned long long wk[4];
    __shared__ unsigned long long fin;
    const int lane = t & 63;
    const int wid  = t >> 6;

    unsigned long long prev = 0;
    bool first = true;
    for (int j = 0; j < PP; ++j) {
        unsigned long long key = 0xFFFFFFFFFFFFFFFFull;
#pragma unroll
        for (int i = 0; i < 32; ++i) {
            unsigned long long kk = ((unsigned long long)o[i] << 32)
                                  | (unsigned)(t + i * 256);
            bool ok = first ? true : (kk > prev);
            if (ok && kk < key) key = kk;
        }
#pragma unroll
        for (int off = 32; off; off >>= 1) {
            unsigned long long v = __shfl_down(key, off, 64);
            if (v < key) key = v;
        }
        if (lane == 0) wk[wid] = key;
        __syncthreads();
        if (t == 0) {
            unsigned long long best = wk[0];
#pragma unroll
            for (int w = 1; w < 4; ++w) if (wk[w] < best) best = wk[w];
            fin = best;
            unsigned idx = (unsigned)(best & 0xFFFFFFFFu);
            out[(size_t)bk * PP + j] = (float)idx;   // exact integer as f32
        }
        __syncthreads();
        prev = fin;
        first = false;
    }
}

extern "C" void kernel_launch(void* const* d_in, const int* in_sizes, int n_in,
                              void* d_out, int out_size, void* d_ws, size_t ws_size,
                              hipStream_t stream) {
    const float* pts = (const float*)d_in[0];
    float* out = (float*)d_out;   // float32: [idx 131072 | centers 12288]

    fps_kernel<<<BB, 1024, 0, stream>>>(pts, out);
    knn_kernel<<<BB * KK, 256, 0, stream>>>(pts, out);
}

// Round 5
// 367.646 us; speedup vs baseline: 1.1212x; 1.1212x over previous
//
#include <hip/hip_runtime.h>

// points [B=32, N=8192, 3] f32. FPS -> K=128 centers/batch (start 0);
// KNN -> P=32 nearest per center, ascending d2, ties by lower index.
// d_out is FLOAT32, flat concat: [idx B*K*P | centers B*K*3].
#define BB 32
#define NN 8192
#define KK 128
#define PP 32
#define IDX_COUNT (BB * KK * PP)   // 131072

// ---------------------------------------------------------------------------
// FPS: one block per batch, 512 threads, 16 pts/thread in registers.
// Bit-parity with numpy scan: d=(dx*dx+dy*dy)+dz*dz (no FMA),
// mind=min(mind,d), next=argmax(mind) first-index tie-break.
// No dynamic register indexing anywhere (match-select publish) -> no scratch.
// 2 barriers/step. Centers written f32 to d_out tail.
// ---------------------------------------------------------------------------
__global__ __launch_bounds__(512) void fps_kernel(
    const float* __restrict__ pts, float* __restrict__ out)
{
#pragma clang fp contract(off)
    const int b = blockIdx.x;
    const int t = threadIdx.x;
    const float* p = pts + (size_t)b * NN * 3;

    float px[16], py[16], pz[16], mind[16];
#pragma unroll
    for (int i = 0; i < 16; ++i) {
        int idx = t + i * 512;
        px[i] = p[idx * 3 + 0];
        py[i] = p[idx * 3 + 1];
        pz[i] = p[idx * 3 + 2];
        mind[i] = __builtin_inff();
    }

    __shared__ float bc[3];
    __shared__ unsigned long long wk[8];
    const int lane = t & 63, wid = t >> 6;

    if (t == 0) {   // start center = point 0 (owned by t=0, i=0: static index)
        bc[0] = px[0]; bc[1] = py[0]; bc[2] = pz[0];
        const int c = b * KK;
        out[IDX_COUNT + c * 3 + 0] = px[0];
        out[IDX_COUNT + c * 3 + 1] = py[0];
        out[IDX_COUNT + c * 3 + 2] = pz[0];
    }
    __syncthreads();

    for (int k = 0; k < KK; ++k) {
        const float lx = bc[0], ly = bc[1], lz = bc[2];

        // local scan: mind update + running argmax (strict > keeps lowest idx)
        float best = -1.0f; unsigned bidx = 0;
#pragma unroll
        for (int i = 0; i < 16; ++i) {
            float dx = px[i] - lx, dy = py[i] - ly, dz = pz[i] - lz;
            float d = (dx * dx + dy * dy) + dz * dz;
            float m = mind[i] < d ? mind[i] : d;
            mind[i] = m;
            if (m > best) { best = m; bidx = (unsigned)(t + i * 512); }
        }
        union { float f; unsigned u; } cv; cv.f = best;   // best >= 0
        unsigned long long key = ((unsigned long long)cv.u << 32)
                               | (0xFFFFFFFFu - bidx);    // max-reduce, low-idx ties
#pragma unroll
        for (int off = 32; off; off >>= 1) {
            unsigned long long o = __shfl_down(key, off, 64);
            if (o > key) key = o;
        }
        if (lane == 0) wk[wid] = key;
        __syncthreads();                                  // A: wk visible
        unsigned long long w = wk[0];
#pragma unroll
        for (int i = 1; i < 8; ++i) { unsigned long long o = wk[i]; if (o > w) w = o; }
        const unsigned last = 0xFFFFFFFFu - (unsigned)(w & 0xFFFFFFFFu);

        if (k < KK - 1 && (last & 511u) == (unsigned)t) { // unique owner
            const unsigned ii = last >> 9;                // 0..15
            float sx = 0.f, sy = 0.f, sz = 0.f;
#pragma unroll
            for (int i = 0; i < 16; ++i) {                // static match-select
                const bool mm = (ii == (unsigned)i);
                sx = mm ? px[i] : sx; sy = mm ? py[i] : sy; sz = mm ? pz[i] : sz;
            }
            bc[0] = sx; bc[1] = sy; bc[2] = sz;
            const int c = b * KK + k + 1;
            out[IDX_COUNT + c * 3 + 0] = sx;
            out[IDX_COUNT + c * 3 + 1] = sy;
            out[IDX_COUNT + c * 3 + 2] = sz;
        }
        __syncthreads();                                  // B: bc publish + wk WAR
    }
}

// ---------------------------------------------------------------------------
// KNN: one block per (b,k), 256 threads, 32 pts/thread. d2 mirrors numpy:
// (cc+pp) - 2*dot, no FMA, -0.0 canonicalized. Exact top-32 via tournament:
// each thread caches its two smallest keys (m1<=m2); per round, global min of
// the 256 m1's is taken from per-wave minima in LDS (only the owner's wave
// recomputes). Owner promotes m2->m1; full O(32) rescan only when both cached
// keys are consumed (~2x per block in expectation). Keys u64 (d2bits,idx):
// unique, ascending order == reference order incl. index tie-break.
// ---------------------------------------------------------------------------
__global__ __launch_bounds__(256) void knn_kernel(
    const float* __restrict__ pts, float* __restrict__ out)
{
#pragma clang fp contract(off)
    const int bk = blockIdx.x;     // b*K + k
    const int b  = bk >> 7;
    const int t  = threadIdx.x;
    const float* p = pts + (size_t)b * NN * 3;

    const float cx = out[IDX_COUNT + bk * 3 + 0];
    const float cy = out[IDX_COUNT + bk * 3 + 1];
    const float cz = out[IDX_COUNT + bk * 3 + 2];
    const float cc = (cx * cx + cy * cy) + cz * cz;

    unsigned o[32];
    unsigned long long m1 = ~0ull, m2 = ~0ull;   // two smallest cached keys
#pragma unroll
    for (int i = 0; i < 32; ++i) {
        const int idx = t + i * 256;
        float x = p[idx * 3 + 0], y = p[idx * 3 + 1], z = p[idx * 3 + 2];
        float pp = (x * x + y * y) + z * z;
        float dot = (cx * x + cy * y) + cz * z;
        float d2 = (cc + pp) - (2.0f * dot);
        d2 = d2 + 0.0f;                          // -0.0 -> +0.0 parity
        union { float f; unsigned u; } cv; cv.f = d2;
        unsigned u = cv.u;
        u = (u & 0x80000000u) ? ~u : (u | 0x80000000u);   // ordered-uint
        o[i] = u;
        const unsigned long long kk = ((unsigned long long)u << 32) | (unsigned)idx;
        const unsigned long long hi = kk < m1 ? m1 : kk;  // max(kk, m1)
        m1 = kk < m1 ? kk : m1;
        m2 = hi < m2 ? hi : m2;
    }

    __shared__ unsigned long long smin[4];       // per-wave min of m1
    const int lane = t & 63, wid = t >> 6;
    {
        unsigned long long k = m1;
#pragma unroll
        for (int off = 32; off; off >>= 1) {
            unsigned long long o2 = __shfl_down(k, off, 64);
            if (o2 < k) k = o2;
        }
        if (lane == 0) smin[wid] = k;
    }
    __syncthreads();

    for (int j = 0; j < PP; ++j) {
        unsigned long long best = smin[0];
#pragma unroll
        for (int w = 1; w < 4; ++w) { unsigned long long o2 = smin[w]; if (o2 < best) best = o2; }
        if (t == 0) out[(size_t)bk * PP + j] = (float)(unsigned)(best & 0xFFFFFFFFu);
        const bool own = (m1 == best);           // unique key -> unique owner
        __syncthreads();                         // A: smin reads done
        if (j < PP - 1) {                        // uniform branch
            if (own) {
                if (m2 != ~0ull) { m1 = m2; m2 = ~0ull; }   // promote backup
                else {                                      // rare full rescan
                    unsigned long long nm = ~0ull;
#pragma unroll
                    for (int i = 0; i < 32; ++i) {
                        const unsigned long long kk =
                            ((unsigned long long)o[i] << 32) | (unsigned)(t + i * 256);
                        if (kk > best && kk < nm) nm = kk;  // > best excludes extracted
                    }
                    m1 = nm;
                }
            }
            if (__ballot(own)) {                 // only owner's wave re-reduces
                unsigned long long k = m1;
#pragma unroll
                for (int off = 32; off; off >>= 1) {
                    unsigned long long o2 = __shfl_down(k, off, 64);
                    if (o2 < k) k = o2;
                }
                if (lane == 0) smin[wid] = k;
            }
            __syncthreads();                     // B: smin update visible
        }
    }
}

extern "C" void kernel_launch(void* const* d_in, const int* in_sizes, int n_in,
                              void* d_out, int out_size, void* d_ws, size_t ws_size,
                              hipStream_t stream) {
    const float* pts = (const float*)d_in[0];
    float* out = (float*)d_out;   // f32: [idx 131072 | centers 12288]

    fps_kernel<<<BB, 512, 0, stream>>>(pts, out);
    knn_kernel<<<BB * KK, 256, 0, stream>>>(pts, out);
}

// Round 6
// 365.321 us; speedup vs baseline: 1.1284x; 1.0064x over previous
//
#include <hip/hip_runtime.h>

// points [B=32, N=8192, 3] f32. FPS -> K=128 centers/batch (start 0);
// KNN -> P=32 nearest per center, ascending d2, ties by lower index.
// d_out is FLOAT32, flat concat: [idx B*K*P | centers B*K*3].
#define BB 32
#define NN 8192
#define KK 128
#define PP 32
#define IDX_COUNT (BB * KK * PP)   // 131072

// ---------------------------------------------------------------------------
// FPS: one block per batch, 512 threads, 16 pts/thread in registers + full
// point cloud staged in LDS (96 KB). Bit-parity with numpy scan:
// d=(dx*dx+dy*dy)+dz*dz (no FMA), mind=min(mind,d), next=argmax first-index.
// ONE barrier per step: block max via per-wave shfl + parity-double-buffered
// wk[k&1][] (WAR-safe: a wave must pass the next step's barrier — which
// requires all waves to have read this step's wk — before rewriting it).
// Winner coords fetched by every thread from LDS (same-address broadcast).
// ---------------------------------------------------------------------------
__global__ __launch_bounds__(512) void fps_kernel(
    const float* __restrict__ pts, float* __restrict__ out)
{
#pragma clang fp contract(off)
    const int b = blockIdx.x;
    const int t = threadIdx.x;
    const float* p = pts + (size_t)b * NN * 3;

    __shared__ float pts3[NN * 3];               // 96 KB
    __shared__ unsigned long long wk[2][8];

    float px[16], py[16], pz[16], mind[16];
#pragma unroll
    for (int i = 0; i < 16; ++i) {
        const int idx = t + i * 512;
        const float x = p[idx * 3 + 0], y = p[idx * 3 + 1], z = p[idx * 3 + 2];
        px[i] = x; py[i] = y; pz[i] = z; mind[i] = __builtin_inff();
        pts3[idx * 3 + 0] = x; pts3[idx * 3 + 1] = y; pts3[idx * 3 + 2] = z;
    }
    __syncthreads();

    float lx = pts3[0], ly = pts3[1], lz = pts3[2];   // start center = pt 0
    if (t == 0) {
        const int c = b * KK;
        out[IDX_COUNT + c * 3 + 0] = lx;
        out[IDX_COUNT + c * 3 + 1] = ly;
        out[IDX_COUNT + c * 3 + 2] = lz;
    }
    const int lane = t & 63, wid = t >> 6;

    for (int k = 0; k < KK - 1; ++k) {          // 127 steps; last argmax unused
        // local scan: mind update + running argmax (strict > keeps lowest idx)
        float best = -1.0f; unsigned bidx = 0;
#pragma unroll
        for (int i = 0; i < 16; ++i) {
            const float dx = px[i] - lx, dy = py[i] - ly, dz = pz[i] - lz;
            const float d = (dx * dx + dy * dy) + dz * dz;
            const float m = mind[i] < d ? mind[i] : d;
            mind[i] = m;
            if (m > best) { best = m; bidx = (unsigned)(t + i * 512); }
        }
        union { float f; unsigned u; } cv; cv.f = best;   // best >= 0
        unsigned long long key = ((unsigned long long)cv.u << 32)
                               | (0xFFFFFFFFu - bidx);    // low-idx tie-break
#pragma unroll
        for (int off = 32; off; off >>= 1) {
            const unsigned long long o = __shfl_down(key, off, 64);
            if (o > key) key = o;
        }
        if (lane == 0) wk[k & 1][wid] = key;
        __syncthreads();
        unsigned long long w = wk[k & 1][0];
#pragma unroll
        for (int i = 1; i < 8; ++i) {
            const unsigned long long o = wk[k & 1][i];
            if (o > w) w = o;
        }
        const unsigned last = 0xFFFFFFFFu - (unsigned)(w & 0xFFFFFFFFu);
        lx = pts3[last * 3 + 0];                 // broadcast reads
        ly = pts3[last * 3 + 1];
        lz = pts3[last * 3 + 2];
        if (t == 0) {
            const int c = b * KK + k + 1;
            out[IDX_COUNT + c * 3 + 0] = lx;
            out[IDX_COUNT + c * 3 + 1] = ly;
            out[IDX_COUNT + c * 3 + 2] = lz;
        }
    }
}

// ---------------------------------------------------------------------------
// KNN: ONE WAVE per center (4 waves/block), 128 pts/lane. No __syncthreads,
// no LDS. d2 mirrors numpy: (cc+pp)-2*dot, no FMA, -0.0 canonicalized.
// Each lane caches its 3 smallest keys sorted (m1<=m2<=m3); per round the
// wave min of m1 is found by a 6-level shfl_xor butterfly (all lanes get it),
// the unique owner promotes; a full 128-pt rescan (keys > extracted best,
// recomputed bit-identically) only when a lane's cache empties (rare).
// Keys u64 (ordered-d2-bits, idx): unique; ascending u64 order == reference
// order including the lower-index tie-break.
// ---------------------------------------------------------------------------
__global__ __launch_bounds__(256) void knn_kernel(
    const float* __restrict__ pts, float* __restrict__ out)
{
#pragma clang fp contract(off)
    const int t = threadIdx.x, lane = t & 63, wid = t >> 6;
    const int bk = blockIdx.x * 4 + wid;     // b*K + k
    const int b  = bk >> 7;
    const float* p = pts + (size_t)b * NN * 3;

    const float cx = out[IDX_COUNT + bk * 3 + 0];
    const float cy = out[IDX_COUNT + bk * 3 + 1];
    const float cz = out[IDX_COUNT + bk * 3 + 2];
    const float cc = (cx * cx + cy * cy) + cz * cz;

    unsigned long long m1 = ~0ull, m2 = ~0ull, m3 = ~0ull;
#pragma unroll 4
    for (int i = 0; i < 128; ++i) {
        const int idx = lane + i * 64;
        const float x = p[idx * 3 + 0], y = p[idx * 3 + 1], z = p[idx * 3 + 2];
        const float pp = (x * x + y * y) + z * z;
        const float dot = (cx * x + cy * y) + cz * z;
        float d2 = (cc + pp) - (2.0f * dot);
        d2 = d2 + 0.0f;                                   // -0.0 -> +0.0
        union { float f; unsigned u; } cv; cv.f = d2;
        unsigned u = cv.u;
        u = (u & 0x80000000u) ? ~u : (u | 0x80000000u);   // ordered-uint
        const unsigned long long kk = ((unsigned long long)u << 32) | (unsigned)idx;
        const bool b1 = kk < m1, b2 = kk < m2, b3 = kk < m3;
        m3 = b2 ? m2 : (b3 ? kk : m3);
        m2 = b1 ? m1 : (b2 ? kk : m2);
        m1 = b1 ? kk : m1;
    }

    float resv = 0.0f;
    for (int j = 0; j < PP; ++j) {
        unsigned long long best = m1;
#pragma unroll
        for (int off = 32; off; off >>= 1) {
            const unsigned long long o = __shfl_xor(best, off, 64);
            if (o < best) best = o;
        }
        if (lane == j) resv = (float)(unsigned)(best & 0xFFFFFFFFu);
        if (m1 == best) { m1 = m2; m2 = m3; m3 = ~0ull; }  // unique owner
        if (m1 == ~0ull) {                                 // rare refill
            // All keys < best were already extracted (global ascending order),
            // so "kk > best" == "not yet extracted".
#pragma unroll 4
            for (int i = 0; i < 128; ++i) {
                const int idx = lane + i * 64;
                const float x = p[idx * 3 + 0], y = p[idx * 3 + 1], z = p[idx * 3 + 2];
                const float pp = (x * x + y * y) + z * z;
                const float dot = (cx * x + cy * y) + cz * z;
                float d2 = (cc + pp) - (2.0f * dot);
                d2 = d2 + 0.0f;
                union { float f; unsigned u; } cv; cv.f = d2;
                unsigned u = cv.u;
                u = (u & 0x80000000u) ? ~u : (u | 0x80000000u);
                const unsigned long long kk =
                    ((unsigned long long)u << 32) | (unsigned)idx;
                if (kk > best) {
                    const bool b1 = kk < m1, b2 = kk < m2, b3 = kk < m3;
                    m3 = b2 ? m2 : (b3 ? kk : m3);
                    m2 = b1 ? m1 : (b2 ? kk : m2);
                    m1 = b1 ? kk : m1;
                }
            }
        }
    }
    if (lane < PP) out[(size_t)bk * PP + lane] = resv;   // coalesced 128B/wave
}

extern "C" void kernel_launch(void* const* d_in, const int* in_sizes, int n_in,
                              void* d_out, int out_size, void* d_ws, size_t ws_size,
                              hipStream_t stream) {
    const float* pts = (const float*)d_in[0];
    float* out = (float*)d_out;   // f32: [idx 131072 | centers 12288]

    fps_kernel<<<BB, 512, 0, stream>>>(pts, out);
    knn_kernel<<<BB * KK / 4, 256, 0, stream>>>(pts, out);
}

// Round 7
// 330.566 us; speedup vs baseline: 1.2470x; 1.1051x over previous
//
#include <hip/hip_runtime.h>

// points [B=32, N=8192, 3] f32. FPS -> K=128 centers/batch (start 0);
// KNN -> P=32 nearest per center, ascending d2, ties by lower index.
// d_out is FLOAT32, flat concat: [idx B*K*P | centers B*K*3].
#define BB 32
#define NN 8192
#define KK 128
#define PP 32
#define IDX_COUNT (BB * KK * PP)   // 131072

// ---------------------------------------------------------------------------
// FPS: one block per batch, 512 threads, 16 pts/thread in registers + full
// cloud in LDS. Bit-parity with numpy scan: d=(dx*dx+dy*dy)+dz*dz (no FMA),
// mind=min(mind,d), next=argmax first-index. ONE barrier/step, parity-
// double-buffered wk. Centers accumulate in LDS cbuf (NO global store inside
// the loop -> no vmcnt(0) drain at the barrier); one bulk write at the end.
// ---------------------------------------------------------------------------
__global__ __launch_bounds__(512) void fps_kernel(
    const float* __restrict__ pts, float* __restrict__ out)
{
#pragma clang fp contract(off)
    const int b = blockIdx.x;
    const int t = threadIdx.x;
    const float* p = pts + (size_t)b * NN * 3;

    __shared__ float pts3[NN * 3];               // 96 KB
    __shared__ float cbuf[KK * 3];               // centers, flushed at end
    __shared__ unsigned long long wk[2][8];

    float px[16], py[16], pz[16], mind[16];
#pragma unroll
    for (int i = 0; i < 16; ++i) {
        const int idx = t + i * 512;
        const float x = p[idx * 3 + 0], y = p[idx * 3 + 1], z = p[idx * 3 + 2];
        px[i] = x; py[i] = y; pz[i] = z; mind[i] = __builtin_inff();
        pts3[idx * 3 + 0] = x; pts3[idx * 3 + 1] = y; pts3[idx * 3 + 2] = z;
    }
    __syncthreads();

    float lx = pts3[0], ly = pts3[1], lz = pts3[2];   // start center = pt 0
    if (t == 0) { cbuf[0] = lx; cbuf[1] = ly; cbuf[2] = lz; }
    const int lane = t & 63, wid = t >> 6;

    for (int k = 0; k < KK - 1; ++k) {          // 127 steps; last argmax unused
        float best = -1.0f; unsigned bidx = 0;
#pragma unroll
        for (int i = 0; i < 16; ++i) {
            const float dx = px[i] - lx, dy = py[i] - ly, dz = pz[i] - lz;
            const float d = (dx * dx + dy * dy) + dz * dz;
            const float m = mind[i] < d ? mind[i] : d;
            mind[i] = m;
            if (m > best) { best = m; bidx = (unsigned)(t + i * 512); }
        }
        union { float f; unsigned u; } cv; cv.f = best;   // best >= 0
        unsigned long long key = ((unsigned long long)cv.u << 32)
                               | (0xFFFFFFFFu - bidx);    // low-idx tie-break
#pragma unroll
        for (int off = 32; off; off >>= 1) {
            const unsigned long long o = __shfl_down(key, off, 64);
            if (o > key) key = o;
        }
        if (lane == 0) wk[k & 1][wid] = key;
        __syncthreads();
        unsigned long long w = wk[k & 1][0];
#pragma unroll
        for (int i = 1; i < 8; ++i) {
            const unsigned long long o = wk[k & 1][i];
            if (o > w) w = o;
        }
        const unsigned last = 0xFFFFFFFFu - (unsigned)(w & 0xFFFFFFFFu);
        lx = pts3[last * 3 + 0];                 // broadcast reads
        ly = pts3[last * 3 + 1];
        lz = pts3[last * 3 + 2];
        if (t == 0) {
            cbuf[(k + 1) * 3 + 0] = lx;
            cbuf[(k + 1) * 3 + 1] = ly;
            cbuf[(k + 1) * 3 + 2] = lz;
        }
    }
    __syncthreads();
    if (t < KK * 3)                              // bulk center write (coalesced)
        out[IDX_COUNT + b * (KK * 3) + t] = cbuf[t];
}

// ---------------------------------------------------------------------------
// KNN: 8 blocks per batch, 256 threads; all 8192 points staged in LDS as
// float4(x,y,z,pp) (128 KB, pp = (x*x+y*y)+z*z bit-parity). Each wave owns 4
// centers; per center: 128 ds_read_b128/lane + exact u64 selection.
// d2 = (cc+pp) - 2*dot, no FMA, -0.0 canonicalized — identical to numpy.
// 4-deep sorted per-lane cache (m1<=..<=m4); refill (rare, ~0.1%/lane) hits
// LDS only. Keys u64 (ordered-d2-bits, idx): unique; ascending u64 order ==
// reference order incl. lower-index tie-break. One barrier total.
// ---------------------------------------------------------------------------
__global__ __launch_bounds__(256) void knn_kernel(
    const float* __restrict__ pts, float* __restrict__ out)
{
#pragma clang fp contract(off)
    const int t = threadIdx.x, lane = t & 63, wid = t >> 6;
    const int blk = blockIdx.x;              // 0..255
    const int b = blk >> 3;                  // batch
    const int cbase = (blk & 7) * 16;        // this block's 16 centers
    const float* p = pts + (size_t)b * NN * 3;

    __shared__ float4 sp[NN];                // 128 KB: x,y,z,pp
    for (int i = 0; i < 32; ++i) {
        const int idx = t + i * 256;
        const float x = p[idx * 3 + 0], y = p[idx * 3 + 1], z = p[idx * 3 + 2];
        const float pp = (x * x + y * y) + z * z;
        sp[idx] = make_float4(x, y, z, pp);
    }
    __syncthreads();

    for (int cg = 0; cg < 4; ++cg) {
        const int bk = b * KK + cbase + wid * 4 + cg;
        const float cx = out[IDX_COUNT + bk * 3 + 0];
        const float cy = out[IDX_COUNT + bk * 3 + 1];
        const float cz = out[IDX_COUNT + bk * 3 + 2];
        const float cc = (cx * cx + cy * cy) + cz * cz;

        unsigned long long m1 = ~0ull, m2 = ~0ull, m3 = ~0ull, m4 = ~0ull;
#pragma unroll 4
        for (int i = 0; i < 128; ++i) {
            const int idx = lane + i * 64;
            const float4 q = sp[idx];
            const float dot = (cx * q.x + cy * q.y) + cz * q.z;
            float d2 = (cc + q.w) - (2.0f * dot);
            d2 = d2 + 0.0f;                                   // -0.0 -> +0.0
            union { float f; unsigned u; } cv; cv.f = d2;
            unsigned u = cv.u;
            u = (u & 0x80000000u) ? ~u : (u | 0x80000000u);   // ordered-uint
            const unsigned long long kk =
                ((unsigned long long)u << 32) | (unsigned)idx;
            const bool b1 = kk < m1, b2 = kk < m2, b3 = kk < m3, b4 = kk < m4;
            m4 = b3 ? m3 : (b4 ? kk : m4);
            m3 = b2 ? m2 : (b3 ? kk : m3);
            m2 = b1 ? m1 : (b2 ? kk : m2);
            m1 = b1 ? kk : m1;
        }

        float resv = 0.0f;
        for (int j = 0; j < PP; ++j) {
            unsigned long long best = m1;
#pragma unroll
            for (int off = 32; off; off >>= 1) {
                const unsigned long long o = __shfl_xor(best, off, 64);
                if (o < best) best = o;
            }
            if (lane == j) resv = (float)(unsigned)(best & 0xFFFFFFFFu);
            if (m1 == best) { m1 = m2; m2 = m3; m3 = m4; m4 = ~0ull; }
            if (m1 == ~0ull) {                   // rare refill, LDS-only
                // keys <= best are exactly the already-extracted ones
#pragma unroll 4
                for (int i = 0; i < 128; ++i) {
                    const int idx = lane + i * 64;
                    const float4 q = sp[idx];
                    const float dot = (cx * q.x + cy * q.y) + cz * q.z;
                    float d2 = (cc + q.w) - (2.0f * dot);
                    d2 = d2 + 0.0f;
                    union { float f; unsigned u; } cv; cv.f = d2;
                    unsigned u = cv.u;
                    u = (u & 0x80000000u) ? ~u : (u | 0x80000000u);
                    const unsigned long long kk =
                        ((unsigned long long)u << 32) | (unsigned)idx;
                    if (kk > best) {
                        const bool b1 = kk < m1, b2 = kk < m2,
                                   b3 = kk < m3, b4 = kk < m4;
                        m4 = b3 ? m3 : (b4 ? kk : m4);
                        m3 = b2 ? m2 : (b3 ? kk : m3);
                        m2 = b1 ? m1 : (b2 ? kk : m2);
                        m1 = b1 ? kk : m1;
                    }
                }
            }
        }
        if (lane < PP) out[(size_t)bk * PP + lane] = resv;   // 128 B/wave
    }
}

extern "C" void kernel_launch(void* const* d_in, const int* in_sizes, int n_in,
                              void* d_out, int out_size, void* d_ws, size_t ws_size,
                              hipStream_t stream) {
    const float* pts = (const float*)d_in[0];
    float* out = (float*)d_out;   // f32: [idx 131072 | centers 12288]

    fps_kernel<<<BB, 512, 0, stream>>>(pts, out);
    knn_kernel<<<BB * 8, 256, 0, stream>>>(pts, out);
}

// Round 8
// 317.727 us; speedup vs baseline: 1.2974x; 1.0404x over previous
//
#include <hip/hip_runtime.h>

// points [B=32, N=8192, 3] f32. FPS -> K=128 centers/batch (start 0);
// KNN -> P=32 nearest per center, ascending d2, ties by lower index.
// d_out is FLOAT32, flat concat: [idx B*K*P | centers B*K*3].
#define BB 32
#define NN 8192
#define KK 128
#define PP 32
#define IDX_COUNT (BB * KK * PP)   // 131072

// ---------------------------------------------------------------------------
// FPS: one block per batch, 512 threads, 16 pts/thread in registers + full
// cloud in LDS. Bit-parity with numpy scan: d=(dx*dx+dy*dy)+dz*dz (no FMA),
// mind=min(mind,d), next=argmax first-index. ONE barrier/step, parity-
// double-buffered wk. Centers accumulate in LDS, one bulk write at the end.
// Also mirrors points to d_ws as float4(x,y,z,pp) for the KNN kernel
// (pp computed contract-off, bit-identical to numpy's (x*x+y*y)+z*z).
// ---------------------------------------------------------------------------
__global__ __launch_bounds__(512) void fps_kernel(
    const float* __restrict__ pts, float* __restrict__ out,
    float4* __restrict__ wsp)                    // may be null
{
#pragma clang fp contract(off)
    const int b = blockIdx.x;
    const int t = threadIdx.x;
    const float* p = pts + (size_t)b * NN * 3;

    __shared__ float pts3[NN * 3];               // 96 KB
    __shared__ float cbuf[KK * 3];
    __shared__ unsigned long long wk[2][8];

    float px[16], py[16], pz[16], mind[16];
#pragma unroll
    for (int i = 0; i < 16; ++i) {
        const int idx = t + i * 512;
        const float x = p[idx * 3 + 0], y = p[idx * 3 + 1], z = p[idx * 3 + 2];
        px[i] = x; py[i] = y; pz[i] = z; mind[i] = __builtin_inff();
        pts3[idx * 3 + 0] = x; pts3[idx * 3 + 1] = y; pts3[idx * 3 + 2] = z;
        if (wsp) wsp[(size_t)b * NN + idx] =
            make_float4(x, y, z, (x * x + y * y) + z * z);
    }
    __syncthreads();

    float lx = pts3[0], ly = pts3[1], lz = pts3[2];   // start center = pt 0
    if (t == 0) { cbuf[0] = lx; cbuf[1] = ly; cbuf[2] = lz; }
    const int lane = t & 63, wid = t >> 6;

    for (int k = 0; k < KK - 1; ++k) {          // 127 steps; last argmax unused
        float best = -1.0f; unsigned bidx = 0;
#pragma unroll
        for (int i = 0; i < 16; ++i) {
            const float dx = px[i] - lx, dy = py[i] - ly, dz = pz[i] - lz;
            const float d = (dx * dx + dy * dy) + dz * dz;
            const float m = mind[i] < d ? mind[i] : d;
            mind[i] = m;
            if (m > best) { best = m; bidx = (unsigned)(t + i * 512); }
        }
        union { float f; unsigned u; } cv; cv.f = best;   // best >= 0
        unsigned long long key = ((unsigned long long)cv.u << 32)
                               | (0xFFFFFFFFu - bidx);    // low-idx tie-break
#pragma unroll
        for (int off = 32; off; off >>= 1) {
            const unsigned long long o = __shfl_down(key, off, 64);
            if (o > key) key = o;
        }
        if (lane == 0) wk[k & 1][wid] = key;
        __syncthreads();
        unsigned long long w = wk[k & 1][0];
#pragma unroll
        for (int i = 1; i < 8; ++i) {
            const unsigned long long o = wk[k & 1][i];
            if (o > w) w = o;
        }
        const unsigned last = 0xFFFFFFFFu - (unsigned)(w & 0xFFFFFFFFu);
        lx = pts3[last * 3 + 0];                 // broadcast reads
        ly = pts3[last * 3 + 1];
        lz = pts3[last * 3 + 2];
        if (t == 0) {
            cbuf[(k + 1) * 3 + 0] = lx;
            cbuf[(k + 1) * 3 + 1] = ly;
            cbuf[(k + 1) * 3 + 2] = lz;
        }
    }
    __syncthreads();
    if (t < KK * 3)
        out[IDX_COUNT + b * (KK * 3) + t] = cbuf[t];
}

// ---------------------------------------------------------------------------
// KNN: ONE WAVE per TWO centers (same batch), 64-thread blocks, 2048 blocks
// (8 blocks/CU -> 8 waves/CU, no LDS, no __syncthreads). Points streamed from
// d_ws float4(x,y,z,pp) (coalesced dwordx4, L2-resident) or raw pts fallback.
// d2 = (cc+pp) - 2*dot, no FMA, -0.0 canonicalized — bit-parity with numpy.
// Per center: 4-deep sorted per-lane key cache; butterfly min extraction
// (two independent chains interleaved for ILP); refill (cache fully empty,
// ~13%/center) rescans from global with kk>best filter — exactness preserved.
// Keys u64 (ordered-d2-bits, idx): unique; ascending == reference order.
// ---------------------------------------------------------------------------
template <bool USE_WS>
__device__ __forceinline__ unsigned long long knn_key(
    const float4* wsp, const float* p, int idx,
    float cx, float cy, float cz, float cc)
{
#pragma clang fp contract(off)
    float x, y, z, pp;
    if (USE_WS) {
        const float4 q = wsp[idx];
        x = q.x; y = q.y; z = q.z; pp = q.w;
    } else {
        x = p[idx * 3 + 0]; y = p[idx * 3 + 1]; z = p[idx * 3 + 2];
        pp = (x * x + y * y) + z * z;
    }
    const float dot = (cx * x + cy * y) + cz * z;
    float d2 = (cc + pp) - (2.0f * dot);
    d2 = d2 + 0.0f;                                   // -0.0 -> +0.0
    union { float f; unsigned u; } cv; cv.f = d2;
    unsigned u = cv.u;
    u = (u & 0x80000000u) ? ~u : (u | 0x80000000u);   // ordered-uint
    return ((unsigned long long)u << 32) | (unsigned)idx;
}

#define CACHE_INS(kk, m1, m2, m3, m4)                                   \
    {                                                                   \
        const bool c1 = (kk) < m1, c2 = (kk) < m2,                      \
                   c3 = (kk) < m3, c4 = (kk) < m4;                      \
        m4 = c3 ? m3 : (c4 ? (kk) : m4);                                \
        m3 = c2 ? m2 : (c3 ? (kk) : m3);                                \
        m2 = c1 ? m1 : (c2 ? (kk) : m2);                                \
        m1 = c1 ? (kk) : m1;                                            \
    }

template <bool USE_WS>
__device__ __forceinline__ void knn_refill(
    const float4* wsp, const float* p, int lane,
    float cx, float cy, float cz, float cc, unsigned long long best,
    unsigned long long& m1, unsigned long long& m2,
    unsigned long long& m3, unsigned long long& m4)
{
    for (int i = 0; i < 128; ++i) {
        const int idx = lane + i * 64;
        const unsigned long long kk =
            knn_key<USE_WS>(wsp, p, idx, cx, cy, cz, cc);
        if (kk > best) CACHE_INS(kk, m1, m2, m3, m4);
    }
}

template <bool USE_WS>
__global__ __launch_bounds__(64) void knn_kernel(
    const float* __restrict__ pts, const float4* __restrict__ wsp_all,
    float* __restrict__ out)
{
#pragma clang fp contract(off)
    const int lane = threadIdx.x;
    const int bkA = blockIdx.x * 2, bkB = bkA + 1;   // same batch (128 even)
    const int b = bkA >> 7;
    const float* p = pts + (size_t)b * NN * 3;
    const float4* wsp = USE_WS ? wsp_all + (size_t)b * NN : nullptr;

    const float axc = out[IDX_COUNT + bkA * 3 + 0];
    const float ayc = out[IDX_COUNT + bkA * 3 + 1];
    const float azc = out[IDX_COUNT + bkA * 3 + 2];
    const float acc = (axc * axc + ayc * ayc) + azc * azc;
    const float bxc = out[IDX_COUNT + bkB * 3 + 0];
    const float byc = out[IDX_COUNT + bkB * 3 + 1];
    const float bzc = out[IDX_COUNT + bkB * 3 + 2];
    const float bcc = (bxc * bxc + byc * byc) + bzc * bzc;

    unsigned long long a1 = ~0ull, a2 = ~0ull, a3 = ~0ull, a4 = ~0ull;
    unsigned long long b1 = ~0ull, b2 = ~0ull, b3 = ~0ull, b4 = ~0ull;
#pragma unroll 4
    for (int i = 0; i < 128; ++i) {
        const int idx = lane + i * 64;
        float x, y, z, pp;
        if (USE_WS) {
            const float4 q = wsp[idx];
            x = q.x; y = q.y; z = q.z; pp = q.w;
        } else {
            x = p[idx * 3 + 0]; y = p[idx * 3 + 1]; z = p[idx * 3 + 2];
            pp = (x * x + y * y) + z * z;
        }
        {   // center A
            const float dot = (axc * x + ayc * y) + azc * z;
            float d2 = (acc + pp) - (2.0f * dot);
            d2 = d2 + 0.0f;
            union { float f; unsigned u; } cv; cv.f = d2;
            unsigned u = cv.u;
            u = (u & 0x80000000u) ? ~u : (u | 0x80000000u);
            const unsigned long long kk =
                ((unsigned long long)u << 32) | (unsigned)idx;
            CACHE_INS(kk, a1, a2, a3, a4);
        }
        {   // center B
            const float dot = (bxc * x + byc * y) + bzc * z;
            float d2 = (bcc + pp) - (2.0f * dot);
            d2 = d2 + 0.0f;
            union { float f; unsigned u; } cv; cv.f = d2;
            unsigned u = cv.u;
            u = (u & 0x80000000u) ? ~u : (u | 0x80000000u);
            const unsigned long long kk =
                ((unsigned long long)u << 32) | (unsigned)idx;
            CACHE_INS(kk, b1, b2, b3, b4);
        }
    }

    float resA = 0.0f, resB = 0.0f;
    for (int j = 0; j < PP; ++j) {
        unsigned long long ba = a1, bb = b1;     // two interleaved butterflies
#pragma unroll
        for (int off = 32; off; off >>= 1) {
            const unsigned long long oa = __shfl_xor(ba, off, 64);
            const unsigned long long ob = __shfl_xor(bb, off, 64);
            if (oa < ba) ba = oa;
            if (ob < bb) bb = ob;
        }
        if (lane == j) {
            resA = (float)(unsigned)(ba & 0xFFFFFFFFu);
            resB = (float)(unsigned)(bb & 0xFFFFFFFFu);
        }
        if (a1 == ba) { a1 = a2; a2 = a3; a3 = a4; a4 = ~0ull; }
        if (a1 == ~0ull)   // cache fully empty -> exact refill (rare)
            knn_refill<USE_WS>(wsp, p, lane, axc, ayc, azc, acc, ba,
                               a1, a2, a3, a4);
        if (b1 == bb) { b1 = b2; b2 = b3; b3 = b4; b4 = ~0ull; }
        if (b1 == ~0ull)
            knn_refill<USE_WS>(wsp, p, lane, bxc, byc, bzc, bcc, bb,
                               b1, b2, b3, b4);
    }
    if (lane < PP) {
        out[(size_t)bkA * PP + lane] = resA;     // 128 B/wave, coalesced
        out[(size_t)bkB * PP + lane] = resB;
    }
}

extern "C" void kernel_launch(void* const* d_in, const int* in_sizes, int n_in,
                              void* d_out, int out_size, void* d_ws, size_t ws_size,
                              hipStream_t stream) {
    const float* pts = (const float*)d_in[0];
    float* out = (float*)d_out;   // f32: [idx 131072 | centers 12288]
    const bool use_ws = ws_size >= (size_t)BB * NN * sizeof(float4);
    float4* wsp = use_ws ? (float4*)d_ws : nullptr;

    fps_kernel<<<BB, 512, 0, stream>>>(pts, out, wsp);
    if (use_ws)
        knn_kernel<true><<<BB * KK / 2, 64, 0, stream>>>(pts, wsp, out);
    else
        knn_kernel<false><<<BB * KK / 2, 64, 0, stream>>>(pts, nullptr, out);
}

// Round 9
// 267.277 us; speedup vs baseline: 1.5423x; 1.1888x over previous
//
#include <hip/hip_runtime.h>

// points [B=32, N=8192, 3] f32. FPS -> K=128 centers/batch (start 0);
// KNN -> P=32 nearest per center, ascending d2, ties by lower index.
// d_out is FLOAT32, flat concat: [idx B*K*P | centers B*K*3].
#define BB 32
#define NN 8192
#define KK 128
#define PP 32
#define IDX_COUNT (BB * KK * PP)   // 131072

// ---- DPP wave64 reductions (VALU-only, ~150 cyc vs ~700 for bpermute) -----
// row_shr:1/2/4/8 then row_bcast15/31; lane 63 holds the result.
// update_dpp(old=self, ...) -> invalid-source lanes keep self (identity).
#define DPP_RED_U64(v, CMP)                                                   \
    {                                                                         \
        _Pragma("unroll")                                                     \
        for (int s = 0; s < 6; ++s) {                                         \
            const int ctrl = (s == 0) ? 0x111 : (s == 1) ? 0x112 :            \
                             (s == 2) ? 0x114 : (s == 3) ? 0x118 :            \
                             (s == 4) ? 0x142 : 0x143;                        \
            unsigned lo = (unsigned)v, hi = (unsigned)(v >> 32);              \
            unsigned slo, shi;                                                \
            switch (ctrl) {                                                   \
            case 0x111:                                                       \
                slo = (unsigned)__builtin_amdgcn_update_dpp((int)lo, (int)lo, 0x111, 0xf, 0xf, false); \
                shi = (unsigned)__builtin_amdgcn_update_dpp((int)hi, (int)hi, 0x111, 0xf, 0xf, false); break; \
            case 0x112:                                                       \
                slo = (unsigned)__builtin_amdgcn_update_dpp((int)lo, (int)lo, 0x112, 0xf, 0xf, false); \
                shi = (unsigned)__builtin_amdgcn_update_dpp((int)hi, (int)hi, 0x112, 0xf, 0xf, false); break; \
            case 0x114:                                                       \
                slo = (unsigned)__builtin_amdgcn_update_dpp((int)lo, (int)lo, 0x114, 0xf, 0xf, false); \
                shi = (unsigned)__builtin_amdgcn_update_dpp((int)hi, (int)hi, 0x114, 0xf, 0xf, false); break; \
            case 0x118:                                                       \
                slo = (unsigned)__builtin_amdgcn_update_dpp((int)lo, (int)lo, 0x118, 0xf, 0xf, false); \
                shi = (unsigned)__builtin_amdgcn_update_dpp((int)hi, (int)hi, 0x118, 0xf, 0xf, false); break; \
            case 0x142:                                                       \
                slo = (unsigned)__builtin_amdgcn_update_dpp((int)lo, (int)lo, 0x142, 0xf, 0xf, false); \
                shi = (unsigned)__builtin_amdgcn_update_dpp((int)hi, (int)hi, 0x142, 0xf, 0xf, false); break; \
            default:                                                          \
                slo = (unsigned)__builtin_amdgcn_update_dpp((int)lo, (int)lo, 0x143, 0xf, 0xf, false); \
                shi = (unsigned)__builtin_amdgcn_update_dpp((int)hi, (int)hi, 0x143, 0xf, 0xf, false); break; \
            }                                                                 \
            const unsigned long long sv = ((unsigned long long)shi << 32) | slo; \
            if (sv CMP v) v = sv;                                             \
        }                                                                     \
    }

__device__ __forceinline__ unsigned long long readlane63_u64(unsigned long long v) {
    const unsigned lo = (unsigned)__builtin_amdgcn_readlane((int)(unsigned)v, 63);
    const unsigned hi = (unsigned)__builtin_amdgcn_readlane((int)(unsigned)(v >> 32), 63);
    return ((unsigned long long)hi << 32) | lo;
}

// ---------------------------------------------------------------------------
// FPS: one block per batch, 512 threads, 16 pts/thread in registers + full
// cloud in LDS. Bit-parity with numpy scan: d=(dx*dx+dy*dy)+dz*dz (no FMA),
// mind=min(mind,d), next=argmax first-index. ONE barrier/step; per-wave max
// via DPP (lane 63 writes partial), cross-wave via 8-slot LDS + parity
// double-buffer. Centers buffered in LDS, one bulk global write at the end.
// Also mirrors points to d_ws as float4(x,y,z,pp) for KNN.
// ---------------------------------------------------------------------------
__global__ __launch_bounds__(512) void fps_kernel(
    const float* __restrict__ pts, float* __restrict__ out,
    float4* __restrict__ wsp)                    // may be null
{
#pragma clang fp contract(off)
    const int b = blockIdx.x;
    const int t = threadIdx.x;
    const float* p = pts + (size_t)b * NN * 3;

    __shared__ float pts3[NN * 3];               // 96 KB
    __shared__ float cbuf[KK * 3];
    __shared__ unsigned long long wk[2][8];

    float px[16], py[16], pz[16], mind[16];
#pragma unroll
    for (int i = 0; i < 16; ++i) {
        const int idx = t + i * 512;
        const float x = p[idx * 3 + 0], y = p[idx * 3 + 1], z = p[idx * 3 + 2];
        px[i] = x; py[i] = y; pz[i] = z; mind[i] = __builtin_inff();
        pts3[idx * 3 + 0] = x; pts3[idx * 3 + 1] = y; pts3[idx * 3 + 2] = z;
        if (wsp) wsp[(size_t)b * NN + idx] =
            make_float4(x, y, z, (x * x + y * y) + z * z);
    }
    __syncthreads();

    float lx = pts3[0], ly = pts3[1], lz = pts3[2];   // start center = pt 0
    if (t == 0) { cbuf[0] = lx; cbuf[1] = ly; cbuf[2] = lz; }
    const int lane = t & 63, wid = t >> 6;

    for (int k = 0; k < KK - 1; ++k) {          // 127 steps; last argmax unused
        float best = -1.0f; unsigned bidx = 0;
#pragma unroll
        for (int i = 0; i < 16; ++i) {
            const float dx = px[i] - lx, dy = py[i] - ly, dz = pz[i] - lz;
            const float d = (dx * dx + dy * dy) + dz * dz;
            const float m = mind[i] < d ? mind[i] : d;
            mind[i] = m;
            if (m > best) { best = m; bidx = (unsigned)(t + i * 512); }
        }
        union { float f; unsigned u; } cv; cv.f = best;   // best >= 0
        unsigned long long key = ((unsigned long long)cv.u << 32)
                               | (0xFFFFFFFFu - bidx);    // low-idx tie-break
        DPP_RED_U64(key, >);                     // lane 63 authoritative
        if (lane == 63) wk[k & 1][wid] = key;
        __syncthreads();
        unsigned long long w = wk[k & 1][0];
#pragma unroll
        for (int i = 1; i < 8; ++i) {
            const unsigned long long o = wk[k & 1][i];
            if (o > w) w = o;
        }
        const unsigned last = 0xFFFFFFFFu - (unsigned)(w & 0xFFFFFFFFu);
        lx = pts3[last * 3 + 0];                 // broadcast reads
        ly = pts3[last * 3 + 1];
        lz = pts3[last * 3 + 2];
        if (t == 0) {
            cbuf[(k + 1) * 3 + 0] = lx;
            cbuf[(k + 1) * 3 + 1] = ly;
            cbuf[(k + 1) * 3 + 2] = lz;
        }
    }
    __syncthreads();
    if (t < KK * 3)
        out[IDX_COUNT + b * (KK * 3) + t] = cbuf[t];
}

// ---------------------------------------------------------------------------
// KNN: 8 blocks/batch, 1024 threads (16 waves = 4/SIMD), full cloud staged in
// 128 KB LDS as float4(x,y,z,pp); exactly ONE center per wave. d2 = (cc+pp)
// - 2*dot, no FMA, -0.0 canonicalized — bit-parity with numpy. Per lane:
// 128 pts, 4-deep sorted u64 key cache; extraction = 32 rounds of DPP
// min-reduce + readlane (no LDS, no barriers, no bpermute). Refill (cache
// empty, ~10%/center) rescans LDS with kk>best filter — exact. Keys u64
// (ordered-d2-bits, idx): unique; ascending == reference order w/ tie-break.
// ---------------------------------------------------------------------------
#define CACHE_INS(kk, m1, m2, m3, m4)                                   \
    {                                                                   \
        const bool c1 = (kk) < m1, c2 = (kk) < m2,                      \
                   c3 = (kk) < m3, c4 = (kk) < m4;                      \
        m4 = c3 ? m3 : (c4 ? (kk) : m4);                                \
        m3 = c2 ? m2 : (c3 ? (kk) : m3);                                \
        m2 = c1 ? m1 : (c2 ? (kk) : m2);                                \
        m1 = c1 ? (kk) : m1;                                            \
    }

template <bool USE_WS>
__global__ __launch_bounds__(1024) void knn_kernel(
    const float* __restrict__ pts, const float4* __restrict__ wsp_all,
    float* __restrict__ out)
{
#pragma clang fp contract(off)
    const int t = threadIdx.x, lane = t & 63, wid = t >> 6;
    const int blk = blockIdx.x;              // 0..255
    const int b = blk >> 3;                  // batch
    const int bk = b * KK + (blk & 7) * 16 + wid;   // this wave's center

    __shared__ float4 sp[NN];                // 128 KB
    if (USE_WS) {
        const float4* wsp = wsp_all + (size_t)b * NN;
#pragma unroll
        for (int i = 0; i < 8; ++i) {
            const int idx = t + i * 1024;
            sp[idx] = wsp[idx];
        }
    } else {
        const float* p = pts + (size_t)b * NN * 3;
#pragma unroll
        for (int i = 0; i < 8; ++i) {
            const int idx = t + i * 1024;
            const float x = p[idx * 3 + 0], y = p[idx * 3 + 1], z = p[idx * 3 + 2];
            sp[idx] = make_float4(x, y, z, (x * x + y * y) + z * z);
        }
    }

    const float cx = out[IDX_COUNT + bk * 3 + 0];
    const float cy = out[IDX_COUNT + bk * 3 + 1];
    const float cz = out[IDX_COUNT + bk * 3 + 2];
    const float cc = (cx * cx + cy * cy) + cz * cz;
    __syncthreads();

    unsigned long long m1 = ~0ull, m2 = ~0ull, m3 = ~0ull, m4 = ~0ull;
#pragma unroll 4
    for (int i = 0; i < 128; ++i) {
        const int idx = lane + i * 64;
        const float4 q = sp[idx];
        const float dot = (cx * q.x + cy * q.y) + cz * q.z;
        float d2 = (cc + q.w) - (2.0f * dot);
        d2 = d2 + 0.0f;                                   // -0.0 -> +0.0
        union { float f; unsigned u; } cv; cv.f = d2;
        unsigned u = cv.u;
        u = (u & 0x80000000u) ? ~u : (u | 0x80000000u);   // ordered-uint
        const unsigned long long kk =
            ((unsigned long long)u << 32) | (unsigned)idx;
        CACHE_INS(kk, m1, m2, m3, m4);
    }

    float resv = 0.0f;
    for (int j = 0; j < PP; ++j) {
        unsigned long long r = m1;
        DPP_RED_U64(r, <);                       // lane 63 authoritative
        const unsigned long long best = readlane63_u64(r);
        if (lane == j) resv = (float)(unsigned)(best & 0xFFFFFFFFu);
        if (m1 == best) { m1 = m2; m2 = m3; m3 = m4; m4 = ~0ull; }
        if (m1 == ~0ull) {                       // rare exact refill (LDS)
            // global extraction is ascending => keys <= best already taken
            for (int i = 0; i < 128; ++i) {
                const int idx = lane + i * 64;
                const float4 q = sp[idx];
                const float dot = (cx * q.x + cy * q.y) + cz * q.z;
                float d2 = (cc + q.w) - (2.0f * dot);
                d2 = d2 + 0.0f;
                union { float f; unsigned u; } cv; cv.f = d2;
                unsigned u = cv.u;
                u = (u & 0x80000000u) ? ~u : (u | 0x80000000u);
                const unsigned long long kk =
                    ((unsigned long long)u << 32) | (unsigned)idx;
                if (kk > best) CACHE_INS(kk, m1, m2, m3, m4);
            }
        }
    }
    if (lane < PP) out[(size_t)bk * PP + lane] = resv;   // 128 B/wave
}

extern "C" void kernel_launch(void* const* d_in, const int* in_sizes, int n_in,
                              void* d_out, int out_size, void* d_ws, size_t ws_size,
                              hipStream_t stream) {
    const float* pts = (const float*)d_in[0];
    float* out = (float*)d_out;   // f32: [idx 131072 | centers 12288]
    const bool use_ws = ws_size >= (size_t)BB * NN * sizeof(float4);
    float4* wsp = use_ws ? (float4*)d_ws : nullptr;

    fps_kernel<<<BB, 512, 0, stream>>>(pts, out, wsp);
    if (use_ws)
        knn_kernel<true><<<BB * 8, 1024, 0, stream>>>(pts, wsp, out);
    else
        knn_kernel<false><<<BB * 8, 1024, 0, stream>>>(pts, nullptr, out);
}